// Round 15
// baseline (292.676 us; speedup 1.0000x reference)
//
#include <hip/hip_runtime.h>

typedef unsigned short u16;
typedef unsigned int u32;
typedef float f32x4 __attribute__((ext_vector_type(4)));
typedef __bf16 bf16x8 __attribute__((ext_vector_type(8)));
typedef unsigned short u16x8 __attribute__((ext_vector_type(8)));
typedef unsigned short u16x4 __attribute__((ext_vector_type(4)));

#define DMODEL 1024
#define DINNER 2048
#define LSEQ   2048
#define BATCH  4
#define NROWS  8192      /* BATCH*LSEQ */
#define NXZ    4096      /* 2*DINNER   */
#define DTR    64
#define DST    16
#define NCHUNK 64
#define LCHUNK 32        /* LSEQ / NCHUNK */
#define CROWS  16        /* conv row-strip per thread */
#define LOG2E  1.44269504088896f

__device__ inline u16 f2bf(float f) {
    unsigned u = __float_as_uint(f);
    u += 0x7fffu + ((u >> 16) & 1u);
    return (u16)(u >> 16);
}
__device__ inline float bf2f(u16 v) {
    return __uint_as_float(((unsigned)v) << 16);
}

__device__ inline f32x4 mfma16(u16x8 a, u16x8 b, f32x4 c) {
    return __builtin_amdgcn_mfma_f32_16x16x32_bf16(
        __builtin_bit_cast(bf16x8, a), __builtin_bit_cast(bf16x8, b), c, 0, 0, 0);
}

__device__ inline float sigmoidf_(float x) { return 1.0f / (1.0f + __expf(-x)); }
__device__ inline float softplus_fast(float x) {
    return (x > 15.0f) ? x : __logf(1.0f + __expf(x));
}
__device__ inline float exp2_raw(float x) { return __builtin_amdgcn_exp2f(x); }

// async global->LDS, 16B per lane; LDS dest = wave-uniform base + lane*16
__device__ inline void gl_lds16(const u16* g, u16* l) {
    __builtin_amdgcn_global_load_lds(
        (const __attribute__((address_space(1))) u32*)(const void*)g,
        (__attribute__((address_space(3))) u32*)(void*)l, 16, 0, 0);
}

// ------- fused LayerNorm (wave-per-row, 4 rows/block) + weight casts ---------
__global__ void prep_k(const float* __restrict__ x, const float* __restrict__ w,
                       const float* __restrict__ b, u16* __restrict__ xn,
                       const float* __restrict__ cs0, u16* __restrict__ cd0, int cn0,
                       const float* __restrict__ cs1, u16* __restrict__ cd1, int cn1,
                       const float* __restrict__ cs2, u16* __restrict__ cd2, int cn2,
                       const float* __restrict__ cs3, u16* __restrict__ cd3, int cn3) {
    int tid = threadIdx.x;
    if (blockIdx.x >= NROWS / 4) {
        int i4 = ((blockIdx.x - NROWS / 4) * 256 + tid) * 4;
        const float* s; u16* d;
        if (i4 < cn0) { s = cs0; d = cd0; }
        else if ((i4 -= cn0) < cn1) { s = cs1; d = cd1; }
        else if ((i4 -= cn1) < cn2) { s = cs2; d = cd2; }
        else if ((i4 -= cn2) < cn3) { s = cs3; d = cd3; }
        else return;
        float4 v = *reinterpret_cast<const float4*>(s + i4);
        u16x4 o;
        o[0] = f2bf(v.x); o[1] = f2bf(v.y); o[2] = f2bf(v.z); o[3] = f2bf(v.w);
        *reinterpret_cast<u16x4*>(d + i4) = o;
        return;
    }
    int row = blockIdx.x * 4 + (tid >> 6);
    int lane = tid & 63;
    const float4* xr = reinterpret_cast<const float4*>(x + (size_t)row * DMODEL);
    float4 v[4];
    float s1 = 0.f, s2 = 0.f;
    #pragma unroll
    for (int q = 0; q < 4; q++) {
        v[q] = xr[lane + 64 * q];
        s1 += v[q].x + v[q].y + v[q].z + v[q].w;
        s2 += v[q].x * v[q].x + v[q].y * v[q].y + v[q].z * v[q].z + v[q].w * v[q].w;
    }
    #pragma unroll
    for (int o = 32; o > 0; o >>= 1) {
        s1 += __shfl_xor(s1, o);
        s2 += __shfl_xor(s2, o);
    }
    float mu = s1 * (1.0f / DMODEL);
    float var = s2 * (1.0f / DMODEL) - mu * mu;
    float rs = rsqrtf(var + 1e-5f);
    const float4* wp = reinterpret_cast<const float4*>(w);
    const float4* bp = reinterpret_cast<const float4*>(b);
    #pragma unroll
    for (int q = 0; q < 4; q++) {
        float4 wv = wp[lane + 64 * q];
        float4 bv = bp[lane + 64 * q];
        u16x4 o;
        o[0] = f2bf((v[q].x - mu) * rs * wv.x + bv.x);
        o[1] = f2bf((v[q].y - mu) * rs * wv.y + bv.y);
        o[2] = f2bf((v[q].z - mu) * rs * wv.z + bv.z);
        o[3] = f2bf((v[q].w - mu) * rs * wv.w + bv.w);
        *reinterpret_cast<u16x4*>(xn + (size_t)row * DMODEL + (lane + 64 * q) * 4) = o;
    }
}

// ========== 256x256 bf16 GEMM for in_proj (M=8192,N=4096,K=1024) =============
__global__ __launch_bounds__(1024, 4)
void gemm256_in(const u16* __restrict__ A, const u16* __restrict__ B,
                u16* __restrict__ xi, u16* __restrict__ zb, int K) {
    __shared__ __align__(16) u16 lds[2][2][256 * 64];
    const int tid = threadIdx.x;
    const int lane = tid & 63, wid = tid >> 6;
    const int wm = wid >> 2, wn = wid & 3;
    const int lh = lane & 15, lq = lane >> 4;

    unsigned id = blockIdx.y * gridDim.x + blockIdx.x;
    unsigned xcd = id & 7, jj = id >> 3;
    const int m0 = ((xcd >> 1) * 8 + (jj >> 3)) * 256;
    const int n0 = ((xcd & 1) * 8 + (jj & 7)) * 256;

    const int srow = tid >> 3;
    const int slane7 = lane & 7;

    f32x4 acc[4][4];
    #pragma unroll
    for (int i = 0; i < 4; i++)
        #pragma unroll
        for (int j = 0; j < 4; j++) acc[i][j] = f32x4{0.f, 0.f, 0.f, 0.f};

    const int nkt = K >> 6;

    auto stage_tile = [&](int bf, int kt) {
        #pragma unroll
        for (int p = 0; p < 2; ++p) {
            int row = p * 128 + srow;
            int kg = slane7 ^ (row & 7);
            gl_lds16(A + (size_t)(m0 + row) * K + kt * 64 + kg * 8,
                     &lds[bf][0][p * 8192 + wid * 512]);
            gl_lds16(B + (size_t)(n0 + row) * K + kt * 64 + kg * 8,
                     &lds[bf][1][p * 8192 + wid * 512]);
        }
    };

    stage_tile(0, 0);

    int cur = 0;
    for (int kt = 0; kt < nkt; ++kt) {
        asm volatile("s_waitcnt vmcnt(0) lgkmcnt(0)" ::: "memory");
        __builtin_amdgcn_s_barrier();
        if (kt + 1 < nkt) stage_tile(cur ^ 1, kt + 1);
        __builtin_amdgcn_s_setprio(1);
        #pragma unroll
        for (int kk = 0; kk < 2; ++kk) {
            u16x8 af[4], bfr[4];
            #pragma unroll
            for (int i = 0; i < 4; i++) {
                int ra = wm * 64 + i * 16 + lh;
                int slot = ((kk << 2) | lq) ^ (ra & 7);
                af[i] = *reinterpret_cast<const u16x8*>(
                    &lds[cur][0][ra * 64 + slot * 8]);
            }
            #pragma unroll
            for (int j = 0; j < 4; j++) {
                int rb = wn * 64 + j * 16 + lh;
                int slot = ((kk << 2) | lq) ^ (rb & 7);
                bfr[j] = *reinterpret_cast<const u16x8*>(
                    &lds[cur][1][rb * 64 + slot * 8]);
            }
            #pragma unroll
            for (int i = 0; i < 4; i++)
                #pragma unroll
                for (int j = 0; j < 4; j++)
                    acc[i][j] = mfma16(af[i], bfr[j], acc[i][j]);
        }
        __builtin_amdgcn_s_setprio(0);
        cur ^= 1;
    }
    #pragma unroll
    for (int ai = 0; ai < 4; ai++)
        #pragma unroll
        for (int bj = 0; bj < 4; bj++)
            #pragma unroll
            for (int r = 0; r < 4; r++) {
                int row = m0 + wm * 64 + ai * 16 + lq * 4 + r;
                int col = n0 + wn * 64 + bj * 16 + lh;
                u16 bv = f2bf(acc[ai][bj][r]);
                if (col < DINNER) xi[(size_t)row * DINNER + col] = bv;
                else              zb[(size_t)row * DINNER + (col - DINNER)] = bv;
            }
}

// ------ 128x128 bf16 GEMM (NT), PIPELINED dbuf — out_proj / dt_proj ----------
// 2x32KB LDS dbuf -> 2 blocks/CU (cross-block overlap retained). ONE
// {vmcnt+lgkmcnt; barrier} per K-tile; stage next tile at top (issue-to-wait
// = full tile of compute). Same XOR-involution staging/read as gemm256_in.
// EPI=1: fp32 Cf = acc + resid[idx]; EPI=2: bf16 xi = softplus(acc+resid[col]).
#define BM 128
#define BN 128
#define BKK 64

template <int EPI>
__global__ __launch_bounds__(256, 2)
void gemm_nt(const u16* __restrict__ A, const u16* __restrict__ B,
             float* __restrict__ Cf, const float* __restrict__ resid,
             u16* __restrict__ xi, u16* __restrict__ zb,
             int M, int N, int K) {
    __shared__ __align__(16) u16 lA[2][BM * BKK];
    __shared__ __align__(16) u16 lB[2][BN * BKK];
    const int tid = threadIdx.x;
    const int lane = tid & 63, wid = tid >> 6;
    const int wr = wid >> 1, wc = wid & 1;
    const int lh = lane & 15, lq = lane >> 4;

    unsigned gx = gridDim.x;
    unsigned id = blockIdx.y * gx + blockIdx.x;
    unsigned cpx = (gridDim.x * gridDim.y) >> 3;
    unsigned swz = (id & 7) * cpx + (id >> 3);
    const int m0 = (swz / gx) * BM, n0 = (swz % gx) * BN;

    const int srow = tid >> 3;          // 0..31, row within 32-row staging pass
    const int slane7 = lane & 7;

    f32x4 acc[4][4];
    #pragma unroll
    for (int i = 0; i < 4; i++)
        #pragma unroll
        for (int j = 0; j < 4; j++) acc[i][j] = f32x4{0.f, 0.f, 0.f, 0.f};

    const int nkt = K / BKK;

    auto stage_tile = [&](int bf, int kt) {
        #pragma unroll
        for (int p = 0; p < 4; ++p) {
            int row = p * 32 + srow;
            int kg = slane7 ^ (row & 7);
            gl_lds16(A + (size_t)(m0 + row) * K + kt * BKK + kg * 8,
                     &lA[bf][p * 2048 + wid * 512]);
            gl_lds16(B + (size_t)(n0 + row) * K + kt * BKK + kg * 8,
                     &lB[bf][p * 2048 + wid * 512]);
        }
    };

    stage_tile(0, 0);

    int cur = 0;
    for (int kt = 0; kt < nkt; ++kt) {
        asm volatile("s_waitcnt vmcnt(0) lgkmcnt(0)" ::: "memory");
        __builtin_amdgcn_s_barrier();
        if (kt + 1 < nkt) stage_tile(cur ^ 1, kt + 1);
        __builtin_amdgcn_s_setprio(1);
        #pragma unroll
        for (int kk = 0; kk < 2; ++kk) {
            u16x8 af[4], bfr[4];
            #pragma unroll
            for (int i = 0; i < 4; i++) {
                int ra = wr * 64 + i * 16 + lh;
                int slot = ((kk << 2) | lq) ^ (ra & 7);
                af[i] = *reinterpret_cast<const u16x8*>(
                    &lA[cur][ra * BKK + slot * 8]);
                int rb = wc * 64 + i * 16 + lh;
                int slotb = ((kk << 2) | lq) ^ (rb & 7);
                bfr[i] = *reinterpret_cast<const u16x8*>(
                    &lB[cur][rb * BKK + slotb * 8]);
            }
            #pragma unroll
            for (int i = 0; i < 4; i++)
                #pragma unroll
                for (int j = 0; j < 4; j++)
                    acc[i][j] = mfma16(af[i], bfr[j], acc[i][j]);
        }
        __builtin_amdgcn_s_setprio(0);
        cur ^= 1;
    }
    #pragma unroll
    for (int i = 0; i < 4; i++)
        #pragma unroll
        for (int j = 0; j < 4; j++)
            #pragma unroll
            for (int r = 0; r < 4; r++) {
                int row = m0 + wr * 64 + i * 16 + lq * 4 + r;
                int col = n0 + wc * 64 + j * 16 + lh;
                float v = acc[i][j][r];
                if (EPI == 1) {
                    size_t idx = (size_t)row * N + col;
                    Cf[idx] = v + resid[idx];
                } else if (EPI == 2) {
                    xi[(size_t)row * N + col] = f2bf(softplus_fast(v + resid[col]));
                } else {
                    u16 bv = f2bf(v);
                    if (col < DINNER)
                        xi[(size_t)row * DINNER + col] = bv;
                    else
                        zb[(size_t)row * DINNER + (col - DINNER)] = bv;
                }
            }
}

// ------- causal depthwise conv (k=4) + SiLU, sliding-window row strips -------
__global__ void conv_silu(const u16* __restrict__ xi, const float* __restrict__ cw,
                          const float* __restrict__ cb, u16* __restrict__ ub) {
    int tid = threadIdx.x;
    int c8 = tid << 3;
    int row0 = blockIdx.x * CROWS;
    int l0 = row0 & (LSEQ - 1);
    float w[8][4], bias[8];
    #pragma unroll
    for (int j = 0; j < 8; j++) {
        bias[j] = cb[c8 + j];
        float4 wv = *reinterpret_cast<const float4*>(cw + (c8 + j) * 4);
        #pragma unroll
        for (int k = 0; k < 4; k++) w[j][k] = ((const float*)&wv)[k];
    }
    const u16* xp = xi + (size_t)row0 * DINNER + c8;
    u16x8 vm3, vm2, vm1;
    if (l0 == 0) {
        #pragma unroll
        for (int j = 0; j < 8; j++) { vm3[j] = 0; vm2[j] = 0; vm1[j] = 0; }
    } else {
        vm3 = *reinterpret_cast<const u16x8*>(xp - 3 * DINNER);
        vm2 = *reinterpret_cast<const u16x8*>(xp - 2 * DINNER);
        vm1 = *reinterpret_cast<const u16x8*>(xp - 1 * DINNER);
    }
    u16* up = ub + (size_t)row0 * DINNER + c8;
    #pragma unroll 4
    for (int r = 0; r < CROWS; ++r) {
        u16x8 v0 = *reinterpret_cast<const u16x8*>(xp); xp += DINNER;
        u16x8 ob;
        #pragma unroll
        for (int j = 0; j < 8; j++) {
            float a = bias[j] + w[j][0] * bf2f(vm3[j]) + w[j][1] * bf2f(vm2[j])
                              + w[j][2] * bf2f(vm1[j]) + w[j][3] * bf2f(v0[j]);
            ob[j] = f2bf(a * sigmoidf_(a));
        }
        *reinterpret_cast<u16x8*>(up) = ob; up += DINNER;
        vm3 = vm2; vm2 = vm1; vm1 = v0;
    }
}

// ---------------- x_proj: (8192x2048) @ (96x2048)^T ------------------------
__global__ void gemm_xdbl(const u16* __restrict__ U, const u16* __restrict__ W,
                          float* __restrict__ xdbl, u16* __restrict__ dtb) {
    __shared__ f32x4 red[4][6][64];
    int tid = threadIdx.x;
    int w = tid >> 6, lane = tid & 63;
    int lh = lane & 15, lq = lane >> 4;
    int mt = blockIdx.x;
    const u16* arow = U + (size_t)(mt * 16 + lh) * DINNER + w * 512 + lq * 8;
    const u16* brow = W + (size_t)lh * DINNER + w * 512 + lq * 8;
    f32x4 acc[6];
    #pragma unroll
    for (int nt = 0; nt < 6; nt++) acc[nt] = f32x4{0.f, 0.f, 0.f, 0.f};
    #pragma unroll 4
    for (int k0 = 0; k0 < 512; k0 += 32) {
        u16x8 a = *reinterpret_cast<const u16x8*>(arow + k0);
        #pragma unroll
        for (int nt = 0; nt < 6; nt++) {
            u16x8 bfr = *reinterpret_cast<const u16x8*>(
                brow + (size_t)nt * 16 * DINNER + k0);
            acc[nt] = mfma16(a, bfr, acc[nt]);
        }
    }
    #pragma unroll
    for (int nt = 0; nt < 6; nt++) red[w][nt][lane] = acc[nt];
    __syncthreads();
    for (int j = tid; j < 384; j += 256) {
        int nt = j >> 6, ln = j & 63;
        f32x4 s = red[0][nt][ln];
        #pragma unroll
        for (int i = 1; i < 4; i++) s += red[i][nt][ln];
        int lh2 = ln & 15, lq2 = ln >> 4;
        #pragma unroll
        for (int r = 0; r < 4; r++) {
            int row = mt * 16 + lq2 * 4 + r;
            int col = nt * 16 + lh2;
            xdbl[(size_t)row * 96 + col] = s[r];
            if (col < DTR) dtb[(size_t)row * DTR + col] = f2bf(s[r]);
        }
    }
}

// ---- load per-channel a[] (log2-scaled) and detect S4D power structure ------
__device__ inline bool load_a_log2(const float* __restrict__ A_log, int d,
                                   float* a2) {
    #pragma unroll
    for (int q = 0; q < 4; q++) {
        float4 av = *reinterpret_cast<const float4*>(A_log + (size_t)d * DST + q * 4);
        #pragma unroll
        for (int r = 0; r < 4; r++)
            a2[q * 4 + r] = -__expf(((const float*)&av)[r]) * LOG2E;
    }
    bool fast = true;
    float a1 = a2[0];
    #pragma unroll
    for (int n = 1; n < DST; n++)
        fast = fast && (__builtin_fabsf(a2[n] - (n + 1) * a1)
                        <= 1e-3f * __builtin_fabsf(a2[n]));
    return fast;
}

// ---------------- selective scan, 3-phase chunked (LDS-staged B/C) ------------
__global__ void scan_p1(const u16* __restrict__ delta, const u16* __restrict__ ub,
                        const float* __restrict__ xdbl, const float* __restrict__ A_log,
                        u16* __restrict__ Qb, float* __restrict__ Sb) {
    __shared__ float lB[LCHUNK * 16];
    int tid = threadIdx.x;
    int g = blockIdx.x * 256 + tid;
    int d = g & (DINNER - 1);
    int b = (g >> 11) & 3;
    int c = g >> 13;
    int rbase = b * LSEQ + c * LCHUNK;
    if (tid < LCHUNK * 4) {
        int t = tid >> 2, j = tid & 3;
        *reinterpret_cast<float4*>(&lB[t * 16 + j * 4]) =
            *reinterpret_cast<const float4*>(xdbl + (size_t)(rbase + t) * 96 + DTR + j * 4);
    }
    float a2[DST];
    bool fast = load_a_log2(A_log, d, a2);
    float a1 = a2[0];
    __syncthreads();
    float h[DST];
    #pragma unroll
    for (int n = 0; n < DST; n++) h[n] = 0.f;
    float ssum = 0.f;
    const u16* dp = delta + (size_t)rbase * DINNER + d;
    const u16* up = ub + (size_t)rbase * DINNER + d;
    if (fast) {
        for (int t = 0; t < LCHUNK; ++t) {
            float dv = bf2f(*dp); dp += DINNER;
            float uv = bf2f(*up); up += DINNER;
            float du = dv * uv;
            ssum += dv;
            float bv[DST];
            #pragma unroll
            for (int q = 0; q < 4; q++)
                *reinterpret_cast<float4*>(bv + q * 4) =
                    *reinterpret_cast<const float4*>(&lB[t * 16 + q * 4]);
            float e1 = exp2_raw(dv * a1);
            float e = e1;
            h[0] = h[0] * e + du * bv[0];
            #pragma unroll
            for (int n = 1; n < DST; n++) {
                e *= e1;
                h[n] = h[n] * e + du * bv[n];
            }
        }
    } else {
        for (int t = 0; t < LCHUNK; ++t) {
            float dv = bf2f(*dp); dp += DINNER;
            float uv = bf2f(*up); up += DINNER;
            float du = dv * uv;
            ssum += dv;
            float bv[DST];
            #pragma unroll
            for (int q = 0; q < 4; q++)
                *reinterpret_cast<float4*>(bv + q * 4) =
                    *reinterpret_cast<const float4*>(&lB[t * 16 + q * 4]);
            #pragma unroll
            for (int n = 0; n < DST; n++)
                h[n] = h[n] * exp2_raw(dv * a2[n]) + du * bv[n];
        }
    }
    size_t base = (size_t)((c * 4 + b) * DST) * DINNER + d;
    #pragma unroll
    for (int n = 0; n < DST; n++) Qb[base + (size_t)n * DINNER] = f2bf(h[n]);
    Sb[(size_t)(c * 4 + b) * DINNER + d] = ssum;
}

__global__ void scan_p2(u16* __restrict__ QH, const float* __restrict__ Sb,
                        const float* __restrict__ A_log) {
    int g = blockIdx.x * 256 + threadIdx.x;   // 131072 threads
    int d = g & (DINNER - 1);
    int n = (g >> 11) & (DST - 1);
    int b = g >> 15;
    float a = -__expf(A_log[(size_t)d * DST + n]) * LOG2E;
    float h = 0.f;
    for (int c = 0; c < NCHUNK; ++c) {
        size_t idx = (size_t)((c * 4 + b) * DST + n) * DINNER + d;
        float s = Sb[(size_t)(c * 4 + b) * DINNER + d];
        float q = bf2f(QH[idx]);
        QH[idx] = f2bf(h);
        h = h * exp2_raw(a * s) + q;
    }
}

__global__ void scan_p3(const u16* __restrict__ delta, const u16* __restrict__ ub,
                        const float* __restrict__ xdbl, const u16* __restrict__ zb,
                        const float* __restrict__ A_log, const float* __restrict__ Dp,
                        const u16* __restrict__ H0, u16* __restrict__ gb) {
    __shared__ float lBC[LCHUNK * 32];
    int tid = threadIdx.x;
    int g = blockIdx.x * 256 + tid;
    int d = g & (DINNER - 1);
    int b = (g >> 11) & 3;
    int c = g >> 13;
    int rbase = b * LSEQ + c * LCHUNK;
    {
        int t = tid >> 3, j = tid & 7;
        *reinterpret_cast<float4*>(&lBC[t * 32 + j * 4]) =
            *reinterpret_cast<const float4*>(xdbl + (size_t)(rbase + t) * 96 + DTR + j * 4);
    }
    float a2[DST];
    bool fast = load_a_log2(A_log, d, a2);
    float a1 = a2[0];
    float Dd = Dp[d];
    __syncthreads();
    float h[DST];
    size_t base = (size_t)((c * 4 + b) * DST) * DINNER + d;
    #pragma unroll
    for (int n = 0; n < DST; n++) h[n] = bf2f(H0[base + (size_t)n * DINNER]);
    const u16* dp = delta + (size_t)rbase * DINNER + d;
    const u16* up = ub + (size_t)rbase * DINNER + d;
    const u16* zp = zb + (size_t)rbase * DINNER + d;
    u16* gp = gb + (size_t)rbase * DINNER + d;
    if (fast) {
        for (int t = 0; t < LCHUNK; ++t) {
            float dv = bf2f(*dp); dp += DINNER;
            float uv = bf2f(*up); up += DINNER;
            float zv = bf2f(*zp); zp += DINNER;
            float du = dv * uv;
            float bv[DST], cv[DST];
            #pragma unroll
            for (int q = 0; q < 4; q++) {
                *reinterpret_cast<float4*>(bv + q * 4) =
                    *reinterpret_cast<const float4*>(&lBC[t * 32 + q * 4]);
                *reinterpret_cast<float4*>(cv + q * 4) =
                    *reinterpret_cast<const float4*>(&lBC[t * 32 + 16 + q * 4]);
            }
            float e1 = exp2_raw(dv * a1);
            float e = e1;
            h[0] = h[0] * e + du * bv[0];
            float y = h[0] * cv[0];
            #pragma unroll
            for (int n = 1; n < DST; n++) {
                e *= e1;
                h[n] = h[n] * e + du * bv[n];
                y += h[n] * cv[n];
            }
            float out = (y + uv * Dd) * (zv * sigmoidf_(zv));
            *gp = f2bf(out); gp += DINNER;
        }
    } else {
        for (int t = 0; t < LCHUNK; ++t) {
            float dv = bf2f(*dp); dp += DINNER;
            float uv = bf2f(*up); up += DINNER;
            float zv = bf2f(*zp); zp += DINNER;
            float du = dv * uv;
            float bv[DST], cv[DST];
            #pragma unroll
            for (int q = 0; q < 4; q++) {
                *reinterpret_cast<float4*>(bv + q * 4) =
                    *reinterpret_cast<const float4*>(&lBC[t * 32 + q * 4]);
                *reinterpret_cast<float4*>(cv + q * 4) =
                    *reinterpret_cast<const float4*>(&lBC[t * 32 + 16 + q * 4]);
            }
            float y = 0.f;
            #pragma unroll
            for (int n = 0; n < DST; n++) {
                h[n] = h[n] * exp2_raw(dv * a2[n]) + du * bv[n];
                y += h[n] * cv[n];
            }
            float out = (y + uv * Dd) * (zv * sigmoidf_(zv));
            *gp = f2bf(out); gp += DINNER;
        }
    }
}

// ---------------- launcher ----------------
extern "C" void kernel_launch(void* const* d_in, const int* in_sizes, int n_in,
                              void* d_out, int out_size, void* d_ws, size_t ws_size,
                              hipStream_t stream) {
    const float* x       = (const float*)d_in[0];
    const float* norm_w  = (const float*)d_in[1];
    const float* norm_b  = (const float*)d_in[2];
    const float* in_w    = (const float*)d_in[3];
    const float* conv_w  = (const float*)d_in[4];
    const float* conv_b  = (const float*)d_in[5];
    const float* xproj_w = (const float*)d_in[6];
    const float* dt_w    = (const float*)d_in[7];
    const float* dt_b    = (const float*)d_in[8];
    const float* A_log   = (const float*)d_in[9];
    const float* Dp      = (const float*)d_in[10];
    const float* out_w   = (const float*)d_in[11];
    float* out = (float*)d_out;
    char* ws = (char*)d_ws;

    size_t off = 0;
    auto carve = [&](size_t bytes) {
        char* p = ws + off;
        off += (bytes + 255) & ~(size_t)255;
        return p;
    };
    u16*   w_in_b  = (u16*)carve((size_t)2 * DINNER * DMODEL * 2);   //  8.4 MB
    u16*   wout_b  = (u16*)carve((size_t)DMODEL * DINNER * 2);       //  4.2 MB
    u16*   xproj_b = (u16*)carve((size_t)96 * DINNER * 2);           //  0.4 MB
    u16*   dtw_b   = (u16*)carve((size_t)DINNER * DTR * 2);          //  0.3 MB
    u16*   xn_b    = (u16*)carve((size_t)NROWS * DMODEL * 2);        // 16.8 MB (later Qb/H0)
    u16*   xi_b    = (u16*)carve((size_t)NROWS * DINNER * 2);        // 33.6 MB (later gb)
    u16*   z_b     = (u16*)carve((size_t)NROWS * DINNER * 2);        // 33.6 MB
    u16*   ub      = (u16*)carve((size_t)NROWS * DINNER * 2);        // 33.6 MB
    u16*   delta   = (u16*)carve((size_t)NROWS * DINNER * 2);        // 33.6 MB
    float* xdbl    = (float*)carve((size_t)NROWS * 96 * 4);          //  3.1 MB
    u16*   dtb     = (u16*)carve((size_t)NROWS * DTR * 2);           //  1.0 MB
    float* Sb      = (float*)carve((size_t)NCHUNK * 4 * DINNER * 4); //  2.0 MB
    u16* QH = xn_b;     // 16.8 MB alias; Qb then H0 in place
    u16* gb = xi_b;     // 33.6 MB alias; p3 -> out_proj

    if (ws_size < off) return;  // scratch too small: fail numerics gracefully

    prep_k<<<NROWS / 4 + 6464, 256, 0, stream>>>(
        x, norm_w, norm_b, xn_b,
        in_w, w_in_b, 2 * DINNER * DMODEL,
        out_w, wout_b, DMODEL * DINNER,
        xproj_w, xproj_b, 96 * DINNER,
        dt_w, dtw_b, DINNER * DTR);
    gemm256_in<<<dim3(16, 32), 1024, 0, stream>>>(xn_b, w_in_b, xi_b, z_b, DMODEL);
    conv_silu<<<NROWS / CROWS, 256, 0, stream>>>(xi_b, conv_w, conv_b, ub);
    gemm_xdbl<<<NROWS / 16, 256, 0, stream>>>(ub, xproj_b, xdbl, dtb);
    gemm_nt<2><<<dim3(DINNER / BN, NROWS / BM), 256, 0, stream>>>(
        dtb, dtw_b, nullptr, dt_b, delta, nullptr, NROWS, DINNER, DTR);
    scan_p1<<<BATCH * NCHUNK * (DINNER / 256), 256, 0, stream>>>(
        delta, ub, xdbl, A_log, QH, Sb);
    scan_p2<<<(BATCH * DST * DINNER) / 256, 256, 0, stream>>>(QH, Sb, A_log);
    scan_p3<<<BATCH * NCHUNK * (DINNER / 256), 256, 0, stream>>>(
        delta, ub, xdbl, z_b, A_log, Dp, QH, gb);
    gemm_nt<1><<<dim3(DMODEL / BN, NROWS / BM), 256, 0, stream>>>(
        gb, wout_b, out, x, nullptr, nullptr, NROWS, DMODEL, DINNER);
}

// Round 16
// 289.455 us; speedup vs baseline: 1.0111x; 1.0111x over previous
//
#include <hip/hip_runtime.h>

typedef unsigned short u16;
typedef unsigned int u32;
typedef float f32x4 __attribute__((ext_vector_type(4)));
typedef __bf16 bf16x8 __attribute__((ext_vector_type(8)));
typedef unsigned short u16x8 __attribute__((ext_vector_type(8)));
typedef unsigned short u16x4 __attribute__((ext_vector_type(4)));

#define DMODEL 1024
#define DINNER 2048
#define LSEQ   2048
#define BATCH  4
#define NROWS  8192      /* BATCH*LSEQ */
#define NXZ    4096      /* 2*DINNER   */
#define DTR    64
#define DST    16
#define NCHUNK 64
#define LCHUNK 32        /* LSEQ / NCHUNK */
#define CROWS  8         /* conv row-strip per thread (16->8: 4 blocks/CU) */
#define LOG2E  1.44269504088896f

__device__ inline u16 f2bf(float f) {
    unsigned u = __float_as_uint(f);
    u += 0x7fffu + ((u >> 16) & 1u);
    return (u16)(u >> 16);
}
__device__ inline float bf2f(u16 v) {
    return __uint_as_float(((unsigned)v) << 16);
}

__device__ inline f32x4 mfma16(u16x8 a, u16x8 b, f32x4 c) {
    return __builtin_amdgcn_mfma_f32_16x16x32_bf16(
        __builtin_bit_cast(bf16x8, a), __builtin_bit_cast(bf16x8, b), c, 0, 0, 0);
}

__device__ inline float sigmoidf_(float x) { return 1.0f / (1.0f + __expf(-x)); }
__device__ inline float softplus_fast(float x) {
    return (x > 15.0f) ? x : __logf(1.0f + __expf(x));
}
__device__ inline float exp2_raw(float x) { return __builtin_amdgcn_exp2f(x); }

// async global->LDS, 16B per lane; LDS dest = wave-uniform base + lane*16
__device__ inline void gl_lds16(const u16* g, u16* l) {
    __builtin_amdgcn_global_load_lds(
        (const __attribute__((address_space(1))) u32*)(const void*)g,
        (__attribute__((address_space(3))) u32*)(void*)l, 16, 0, 0);
}

// ------- fused LayerNorm (wave-per-row, 4 rows/block) + weight casts ---------
__global__ void prep_k(const float* __restrict__ x, const float* __restrict__ w,
                       const float* __restrict__ b, u16* __restrict__ xn,
                       const float* __restrict__ cs0, u16* __restrict__ cd0, int cn0,
                       const float* __restrict__ cs1, u16* __restrict__ cd1, int cn1,
                       const float* __restrict__ cs2, u16* __restrict__ cd2, int cn2,
                       const float* __restrict__ cs3, u16* __restrict__ cd3, int cn3) {
    int tid = threadIdx.x;
    if (blockIdx.x >= NROWS / 4) {
        int i4 = ((blockIdx.x - NROWS / 4) * 256 + tid) * 4;
        const float* s; u16* d;
        if (i4 < cn0) { s = cs0; d = cd0; }
        else if ((i4 -= cn0) < cn1) { s = cs1; d = cd1; }
        else if ((i4 -= cn1) < cn2) { s = cs2; d = cd2; }
        else if ((i4 -= cn2) < cn3) { s = cs3; d = cd3; }
        else return;
        float4 v = *reinterpret_cast<const float4*>(s + i4);
        u16x4 o;
        o[0] = f2bf(v.x); o[1] = f2bf(v.y); o[2] = f2bf(v.z); o[3] = f2bf(v.w);
        *reinterpret_cast<u16x4*>(d + i4) = o;
        return;
    }
    int row = blockIdx.x * 4 + (tid >> 6);
    int lane = tid & 63;
    const float4* xr = reinterpret_cast<const float4*>(x + (size_t)row * DMODEL);
    float4 v[4];
    float s1 = 0.f, s2 = 0.f;
    #pragma unroll
    for (int q = 0; q < 4; q++) {
        v[q] = xr[lane + 64 * q];
        s1 += v[q].x + v[q].y + v[q].z + v[q].w;
        s2 += v[q].x * v[q].x + v[q].y * v[q].y + v[q].z * v[q].z + v[q].w * v[q].w;
    }
    #pragma unroll
    for (int o = 32; o > 0; o >>= 1) {
        s1 += __shfl_xor(s1, o);
        s2 += __shfl_xor(s2, o);
    }
    float mu = s1 * (1.0f / DMODEL);
    float var = s2 * (1.0f / DMODEL) - mu * mu;
    float rs = rsqrtf(var + 1e-5f);
    const float4* wp = reinterpret_cast<const float4*>(w);
    const float4* bp = reinterpret_cast<const float4*>(b);
    #pragma unroll
    for (int q = 0; q < 4; q++) {
        float4 wv = wp[lane + 64 * q];
        float4 bv = bp[lane + 64 * q];
        u16x4 o;
        o[0] = f2bf((v[q].x - mu) * rs * wv.x + bv.x);
        o[1] = f2bf((v[q].y - mu) * rs * wv.y + bv.y);
        o[2] = f2bf((v[q].z - mu) * rs * wv.z + bv.z);
        o[3] = f2bf((v[q].w - mu) * rs * wv.w + bv.w);
        *reinterpret_cast<u16x4*>(xn + (size_t)row * DMODEL + (lane + 64 * q) * 4) = o;
    }
}

// ========== 256x256 bf16 GEMM for in_proj (M=8192,N=4096,K=1024) =============
__global__ __launch_bounds__(1024, 4)
void gemm256_in(const u16* __restrict__ A, const u16* __restrict__ B,
                u16* __restrict__ xi, u16* __restrict__ zb, int K) {
    __shared__ __align__(16) u16 lds[2][2][256 * 64];
    const int tid = threadIdx.x;
    const int lane = tid & 63, wid = tid >> 6;
    const int wm = wid >> 2, wn = wid & 3;
    const int lh = lane & 15, lq = lane >> 4;

    unsigned id = blockIdx.y * gridDim.x + blockIdx.x;
    unsigned xcd = id & 7, jj = id >> 3;
    const int m0 = ((xcd >> 1) * 8 + (jj >> 3)) * 256;
    const int n0 = ((xcd & 1) * 8 + (jj & 7)) * 256;

    const int srow = tid >> 3;
    const int slane7 = lane & 7;

    f32x4 acc[4][4];
    #pragma unroll
    for (int i = 0; i < 4; i++)
        #pragma unroll
        for (int j = 0; j < 4; j++) acc[i][j] = f32x4{0.f, 0.f, 0.f, 0.f};

    const int nkt = K >> 6;

    auto stage_tile = [&](int bf, int kt) {
        #pragma unroll
        for (int p = 0; p < 2; ++p) {
            int row = p * 128 + srow;
            int kg = slane7 ^ (row & 7);
            gl_lds16(A + (size_t)(m0 + row) * K + kt * 64 + kg * 8,
                     &lds[bf][0][p * 8192 + wid * 512]);
            gl_lds16(B + (size_t)(n0 + row) * K + kt * 64 + kg * 8,
                     &lds[bf][1][p * 8192 + wid * 512]);
        }
    };

    stage_tile(0, 0);

    int cur = 0;
    for (int kt = 0; kt < nkt; ++kt) {
        asm volatile("s_waitcnt vmcnt(0) lgkmcnt(0)" ::: "memory");
        __builtin_amdgcn_s_barrier();
        if (kt + 1 < nkt) stage_tile(cur ^ 1, kt + 1);
        __builtin_amdgcn_s_setprio(1);
        #pragma unroll
        for (int kk = 0; kk < 2; ++kk) {
            u16x8 af[4], bfr[4];
            #pragma unroll
            for (int i = 0; i < 4; i++) {
                int ra = wm * 64 + i * 16 + lh;
                int slot = ((kk << 2) | lq) ^ (ra & 7);
                af[i] = *reinterpret_cast<const u16x8*>(
                    &lds[cur][0][ra * 64 + slot * 8]);
            }
            #pragma unroll
            for (int j = 0; j < 4; j++) {
                int rb = wn * 64 + j * 16 + lh;
                int slot = ((kk << 2) | lq) ^ (rb & 7);
                bfr[j] = *reinterpret_cast<const u16x8*>(
                    &lds[cur][1][rb * 64 + slot * 8]);
            }
            #pragma unroll
            for (int i = 0; i < 4; i++)
                #pragma unroll
                for (int j = 0; j < 4; j++)
                    acc[i][j] = mfma16(af[i], bfr[j], acc[i][j]);
        }
        __builtin_amdgcn_s_setprio(0);
        cur ^= 1;
    }
    #pragma unroll
    for (int ai = 0; ai < 4; ai++)
        #pragma unroll
        for (int bj = 0; bj < 4; bj++)
            #pragma unroll
            for (int r = 0; r < 4; r++) {
                int row = m0 + wm * 64 + ai * 16 + lq * 4 + r;
                int col = n0 + wn * 64 + bj * 16 + lh;
                u16 bv = f2bf(acc[ai][bj][r]);
                if (col < DINNER) xi[(size_t)row * DINNER + col] = bv;
                else              zb[(size_t)row * DINNER + (col - DINNER)] = bv;
            }
}

// ---------------- 128x128 bf16 MFMA GEMM (NT) — out_proj / dt_proj ------------
// (R14 version: single-buffer, 2 barriers/K-tile — measured best config)
// EPI=1: write fp32 -> Cf = acc + resid[idx]
// EPI=2: write bf16 -> xi = softplus(acc + resid[col])   (dt_proj fused)
#define BM 128
#define BN 128
#define BKK 64

template <int EPI>
__global__ void gemm_nt(const u16* __restrict__ A, const u16* __restrict__ B,
                        float* __restrict__ Cf, const float* __restrict__ resid,
                        u16* __restrict__ xi, u16* __restrict__ zb,
                        int M, int N, int K) {
    __shared__ __align__(16) u16 lA[BM * BKK];
    __shared__ __align__(16) u16 lB[BN * BKK];
    const int tid = threadIdx.x;
    const int lane = tid & 63, wid = tid >> 6;
    const int wr = wid >> 1, wc = wid & 1;
    const int lh = lane & 15, lq = lane >> 4;

    unsigned gx = gridDim.x;
    unsigned id = blockIdx.y * gx + blockIdx.x;
    unsigned cpx = (gridDim.x * gridDim.y) >> 3;
    unsigned swz = (id & 7) * cpx + (id >> 3);
    const int m0 = (swz / gx) * BM, n0 = (swz % gx) * BN;

    const int srow = (wid * 8) + (lane >> 3);
    const int skg  = (lane & 7) ^ (srow & 7);

    f32x4 acc[4][4];
    #pragma unroll
    for (int i = 0; i < 4; i++)
        #pragma unroll
        for (int j = 0; j < 4; j++) acc[i][j] = f32x4{0.f, 0.f, 0.f, 0.f};

    const int nkt = K / BKK;
    for (int kt = 0; kt < nkt; ++kt) {
        __syncthreads();
        #pragma unroll
        for (int p = 0; p < 4; ++p) {
            int row = p * 32 + srow;
            gl_lds16(A + (size_t)(m0 + row) * K + kt * BKK + skg * 8,
                     lA + (p * 4 + wid) * 512);
            gl_lds16(B + (size_t)(n0 + row) * K + kt * BKK + skg * 8,
                     lB + (p * 4 + wid) * 512);
        }
        __syncthreads();
        #pragma unroll
        for (int kk = 0; kk < 2; ++kk) {
            u16x8 af[4], bf[4];
            #pragma unroll
            for (int i = 0; i < 4; i++) {
                int ra = wr * 64 + i * 16 + lh;
                af[i] = *reinterpret_cast<const u16x8*>(
                    lA + ra * BKK + ((((kk << 2) | lq) ^ (ra & 7)) * 8));
                int rb = wc * 64 + i * 16 + lh;
                bf[i] = *reinterpret_cast<const u16x8*>(
                    lB + rb * BKK + ((((kk << 2) | lq) ^ (rb & 7)) * 8));
            }
            #pragma unroll
            for (int i = 0; i < 4; i++)
                #pragma unroll
                for (int j = 0; j < 4; j++)
                    acc[i][j] = mfma16(af[i], bf[j], acc[i][j]);
        }
    }
    #pragma unroll
    for (int i = 0; i < 4; i++)
        #pragma unroll
        for (int j = 0; j < 4; j++)
            #pragma unroll
            for (int r = 0; r < 4; r++) {
                int row = m0 + wr * 64 + i * 16 + lq * 4 + r;
                int col = n0 + wc * 64 + j * 16 + lh;
                float v = acc[i][j][r];
                if (EPI == 1) {
                    size_t idx = (size_t)row * N + col;
                    Cf[idx] = v + resid[idx];
                } else if (EPI == 2) {
                    xi[(size_t)row * N + col] = f2bf(softplus_fast(v + resid[col]));
                } else {
                    u16 bv = f2bf(v);
                    if (col < DINNER)
                        xi[(size_t)row * DINNER + col] = bv;
                    else
                        zb[(size_t)row * DINNER + (col - DINNER)] = bv;
                }
            }
}

// ------- causal depthwise conv (k=4) + SiLU, sliding-window row strips -------
__global__ void conv_silu(const u16* __restrict__ xi, const float* __restrict__ cw,
                          const float* __restrict__ cb, u16* __restrict__ ub) {
    int tid = threadIdx.x;
    int c8 = tid << 3;
    int row0 = blockIdx.x * CROWS;
    int l0 = row0 & (LSEQ - 1);
    float w[8][4], bias[8];
    #pragma unroll
    for (int j = 0; j < 8; j++) {
        bias[j] = cb[c8 + j];
        float4 wv = *reinterpret_cast<const float4*>(cw + (c8 + j) * 4);
        #pragma unroll
        for (int k = 0; k < 4; k++) w[j][k] = ((const float*)&wv)[k];
    }
    const u16* xp = xi + (size_t)row0 * DINNER + c8;
    u16x8 vm3, vm2, vm1;
    if (l0 == 0) {
        #pragma unroll
        for (int j = 0; j < 8; j++) { vm3[j] = 0; vm2[j] = 0; vm1[j] = 0; }
    } else {
        vm3 = *reinterpret_cast<const u16x8*>(xp - 3 * DINNER);
        vm2 = *reinterpret_cast<const u16x8*>(xp - 2 * DINNER);
        vm1 = *reinterpret_cast<const u16x8*>(xp - 1 * DINNER);
    }
    u16* up = ub + (size_t)row0 * DINNER + c8;
    #pragma unroll
    for (int r = 0; r < CROWS; ++r) {
        u16x8 v0 = *reinterpret_cast<const u16x8*>(xp); xp += DINNER;
        u16x8 ob;
        #pragma unroll
        for (int j = 0; j < 8; j++) {
            float a = bias[j] + w[j][0] * bf2f(vm3[j]) + w[j][1] * bf2f(vm2[j])
                              + w[j][2] * bf2f(vm1[j]) + w[j][3] * bf2f(v0[j]);
            ob[j] = f2bf(a * sigmoidf_(a));
        }
        *reinterpret_cast<u16x8*>(up) = ob; up += DINNER;
        vm3 = vm2; vm2 = vm1; vm1 = v0;
    }
}

// ---------------- x_proj: (8192x2048) @ (96x2048)^T ------------------------
__global__ void gemm_xdbl(const u16* __restrict__ U, const u16* __restrict__ W,
                          float* __restrict__ xdbl, u16* __restrict__ dtb) {
    __shared__ f32x4 red[4][6][64];
    int tid = threadIdx.x;
    int w = tid >> 6, lane = tid & 63;
    int lh = lane & 15, lq = lane >> 4;
    int mt = blockIdx.x;
    const u16* arow = U + (size_t)(mt * 16 + lh) * DINNER + w * 512 + lq * 8;
    const u16* brow = W + (size_t)lh * DINNER + w * 512 + lq * 8;
    f32x4 acc[6];
    #pragma unroll
    for (int nt = 0; nt < 6; nt++) acc[nt] = f32x4{0.f, 0.f, 0.f, 0.f};
    #pragma unroll 4
    for (int k0 = 0; k0 < 512; k0 += 32) {
        u16x8 a = *reinterpret_cast<const u16x8*>(arow + k0);
        #pragma unroll
        for (int nt = 0; nt < 6; nt++) {
            u16x8 bfr = *reinterpret_cast<const u16x8*>(
                brow + (size_t)nt * 16 * DINNER + k0);
            acc[nt] = mfma16(a, bfr, acc[nt]);
        }
    }
    #pragma unroll
    for (int nt = 0; nt < 6; nt++) red[w][nt][lane] = acc[nt];
    __syncthreads();
    for (int j = tid; j < 384; j += 256) {
        int nt = j >> 6, ln = j & 63;
        f32x4 s = red[0][nt][ln];
        #pragma unroll
        for (int i = 1; i < 4; i++) s += red[i][nt][ln];
        int lh2 = ln & 15, lq2 = ln >> 4;
        #pragma unroll
        for (int r = 0; r < 4; r++) {
            int row = mt * 16 + lq2 * 4 + r;
            int col = nt * 16 + lh2;
            xdbl[(size_t)row * 96 + col] = s[r];
            if (col < DTR) dtb[(size_t)row * DTR + col] = f2bf(s[r]);
        }
    }
}

// ---- load per-channel a[] (log2-scaled) and detect S4D power structure ------
__device__ inline bool load_a_log2(const float* __restrict__ A_log, int d,
                                   float* a2) {
    #pragma unroll
    for (int q = 0; q < 4; q++) {
        float4 av = *reinterpret_cast<const float4*>(A_log + (size_t)d * DST + q * 4);
        #pragma unroll
        for (int r = 0; r < 4; r++)
            a2[q * 4 + r] = -__expf(((const float*)&av)[r]) * LOG2E;
    }
    bool fast = true;
    float a1 = a2[0];
    #pragma unroll
    for (int n = 1; n < DST; n++)
        fast = fast && (__builtin_fabsf(a2[n] - (n + 1) * a1)
                        <= 1e-3f * __builtin_fabsf(a2[n]));
    return fast;
}

// ---------------- selective scan, 3-phase chunked (LDS-staged B/C) ------------
__global__ void scan_p1(const u16* __restrict__ delta, const u16* __restrict__ ub,
                        const float* __restrict__ xdbl, const float* __restrict__ A_log,
                        u16* __restrict__ Qb, float* __restrict__ Sb) {
    __shared__ float lB[LCHUNK * 16];
    int tid = threadIdx.x;
    int g = blockIdx.x * 256 + tid;
    int d = g & (DINNER - 1);
    int b = (g >> 11) & 3;
    int c = g >> 13;
    int rbase = b * LSEQ + c * LCHUNK;
    if (tid < LCHUNK * 4) {
        int t = tid >> 2, j = tid & 3;
        *reinterpret_cast<float4*>(&lB[t * 16 + j * 4]) =
            *reinterpret_cast<const float4*>(xdbl + (size_t)(rbase + t) * 96 + DTR + j * 4);
    }
    float a2[DST];
    bool fast = load_a_log2(A_log, d, a2);
    float a1 = a2[0];
    __syncthreads();
    float h[DST];
    #pragma unroll
    for (int n = 0; n < DST; n++) h[n] = 0.f;
    float ssum = 0.f;
    const u16* dp = delta + (size_t)rbase * DINNER + d;
    const u16* up = ub + (size_t)rbase * DINNER + d;
    if (fast) {
        for (int t = 0; t < LCHUNK; ++t) {
            float dv = bf2f(*dp); dp += DINNER;
            float uv = bf2f(*up); up += DINNER;
            float du = dv * uv;
            ssum += dv;
            float bv[DST];
            #pragma unroll
            for (int q = 0; q < 4; q++)
                *reinterpret_cast<float4*>(bv + q * 4) =
                    *reinterpret_cast<const float4*>(&lB[t * 16 + q * 4]);
            float e1 = exp2_raw(dv * a1);
            float e = e1;
            h[0] = h[0] * e + du * bv[0];
            #pragma unroll
            for (int n = 1; n < DST; n++) {
                e *= e1;
                h[n] = h[n] * e + du * bv[n];
            }
        }
    } else {
        for (int t = 0; t < LCHUNK; ++t) {
            float dv = bf2f(*dp); dp += DINNER;
            float uv = bf2f(*up); up += DINNER;
            float du = dv * uv;
            ssum += dv;
            float bv[DST];
            #pragma unroll
            for (int q = 0; q < 4; q++)
                *reinterpret_cast<float4*>(bv + q * 4) =
                    *reinterpret_cast<const float4*>(&lB[t * 16 + q * 4]);
            #pragma unroll
            for (int n = 0; n < DST; n++)
                h[n] = h[n] * exp2_raw(dv * a2[n]) + du * bv[n];
        }
    }
    size_t base = (size_t)((c * 4 + b) * DST) * DINNER + d;
    #pragma unroll
    for (int n = 0; n < DST; n++) Qb[base + (size_t)n * DINNER] = f2bf(h[n]);
    Sb[(size_t)(c * 4 + b) * DINNER + d] = ssum;
}

__global__ void scan_p2(u16* __restrict__ QH, const float* __restrict__ Sb,
                        const float* __restrict__ A_log) {
    int g = blockIdx.x * 256 + threadIdx.x;   // 131072 threads
    int d = g & (DINNER - 1);
    int n = (g >> 11) & (DST - 1);
    int b = g >> 15;
    float a = -__expf(A_log[(size_t)d * DST + n]) * LOG2E;
    float h = 0.f;
    for (int c = 0; c < NCHUNK; ++c) {
        size_t idx = (size_t)((c * 4 + b) * DST + n) * DINNER + d;
        float s = Sb[(size_t)(c * 4 + b) * DINNER + d];
        float q = bf2f(QH[idx]);
        QH[idx] = f2bf(h);
        h = h * exp2_raw(a * s) + q;
    }
}

__global__ void scan_p3(const u16* __restrict__ delta, const u16* __restrict__ ub,
                        const float* __restrict__ xdbl, const u16* __restrict__ zb,
                        const float* __restrict__ A_log, const float* __restrict__ Dp,
                        const u16* __restrict__ H0, u16* __restrict__ gb) {
    __shared__ float lBC[LCHUNK * 32];
    int tid = threadIdx.x;
    int g = blockIdx.x * 256 + tid;
    int d = g & (DINNER - 1);
    int b = (g >> 11) & 3;
    int c = g >> 13;
    int rbase = b * LSEQ + c * LCHUNK;
    {
        int t = tid >> 3, j = tid & 7;
        *reinterpret_cast<float4*>(&lBC[t * 32 + j * 4]) =
            *reinterpret_cast<const float4*>(xdbl + (size_t)(rbase + t) * 96 + DTR + j * 4);
    }
    float a2[DST];
    bool fast = load_a_log2(A_log, d, a2);
    float a1 = a2[0];
    float Dd = Dp[d];
    __syncthreads();
    float h[DST];
    size_t base = (size_t)((c * 4 + b) * DST) * DINNER + d;
    #pragma unroll
    for (int n = 0; n < DST; n++) h[n] = bf2f(H0[base + (size_t)n * DINNER]);
    const u16* dp = delta + (size_t)rbase * DINNER + d;
    const u16* up = ub + (size_t)rbase * DINNER + d;
    const u16* zp = zb + (size_t)rbase * DINNER + d;
    u16* gp = gb + (size_t)rbase * DINNER + d;
    if (fast) {
        for (int t = 0; t < LCHUNK; ++t) {
            float dv = bf2f(*dp); dp += DINNER;
            float uv = bf2f(*up); up += DINNER;
            float zv = bf2f(*zp); zp += DINNER;
            float du = dv * uv;
            float bv[DST], cv[DST];
            #pragma unroll
            for (int q = 0; q < 4; q++) {
                *reinterpret_cast<float4*>(bv + q * 4) =
                    *reinterpret_cast<const float4*>(&lBC[t * 32 + q * 4]);
                *reinterpret_cast<float4*>(cv + q * 4) =
                    *reinterpret_cast<const float4*>(&lBC[t * 32 + 16 + q * 4]);
            }
            float e1 = exp2_raw(dv * a1);
            float e = e1;
            h[0] = h[0] * e + du * bv[0];
            float y = h[0] * cv[0];
            #pragma unroll
            for (int n = 1; n < DST; n++) {
                e *= e1;
                h[n] = h[n] * e + du * bv[n];
                y += h[n] * cv[n];
            }
            float out = (y + uv * Dd) * (zv * sigmoidf_(zv));
            *gp = f2bf(out); gp += DINNER;
        }
    } else {
        for (int t = 0; t < LCHUNK; ++t) {
            float dv = bf2f(*dp); dp += DINNER;
            float uv = bf2f(*up); up += DINNER;
            float zv = bf2f(*zp); zp += DINNER;
            float du = dv * uv;
            float bv[DST], cv[DST];
            #pragma unroll
            for (int q = 0; q < 4; q++) {
                *reinterpret_cast<float4*>(bv + q * 4) =
                    *reinterpret_cast<const float4*>(&lBC[t * 32 + q * 4]);
                *reinterpret_cast<float4*>(cv + q * 4) =
                    *reinterpret_cast<const float4*>(&lBC[t * 32 + 16 + q * 4]);
            }
            float y = 0.f;
            #pragma unroll
            for (int n = 0; n < DST; n++) {
                h[n] = h[n] * exp2_raw(dv * a2[n]) + du * bv[n];
                y += h[n] * cv[n];
            }
            float out = (y + uv * Dd) * (zv * sigmoidf_(zv));
            *gp = f2bf(out); gp += DINNER;
        }
    }
}

// ---------------- launcher ----------------
extern "C" void kernel_launch(void* const* d_in, const int* in_sizes, int n_in,
                              void* d_out, int out_size, void* d_ws, size_t ws_size,
                              hipStream_t stream) {
    const float* x       = (const float*)d_in[0];
    const float* norm_w  = (const float*)d_in[1];
    const float* norm_b  = (const float*)d_in[2];
    const float* in_w    = (const float*)d_in[3];
    const float* conv_w  = (const float*)d_in[4];
    const float* conv_b  = (const float*)d_in[5];
    const float* xproj_w = (const float*)d_in[6];
    const float* dt_w    = (const float*)d_in[7];
    const float* dt_b    = (const float*)d_in[8];
    const float* A_log   = (const float*)d_in[9];
    const float* Dp      = (const float*)d_in[10];
    const float* out_w   = (const float*)d_in[11];
    float* out = (float*)d_out;
    char* ws = (char*)d_ws;

    size_t off = 0;
    auto carve = [&](size_t bytes) {
        char* p = ws + off;
        off += (bytes + 255) & ~(size_t)255;
        return p;
    };
    u16*   w_in_b  = (u16*)carve((size_t)2 * DINNER * DMODEL * 2);   //  8.4 MB
    u16*   wout_b  = (u16*)carve((size_t)DMODEL * DINNER * 2);       //  4.2 MB
    u16*   xproj_b = (u16*)carve((size_t)96 * DINNER * 2);           //  0.4 MB
    u16*   dtw_b   = (u16*)carve((size_t)DINNER * DTR * 2);          //  0.3 MB
    u16*   xn_b    = (u16*)carve((size_t)NROWS * DMODEL * 2);        // 16.8 MB (later Qb/H0)
    u16*   xi_b    = (u16*)carve((size_t)NROWS * DINNER * 2);        // 33.6 MB (later gb)
    u16*   z_b     = (u16*)carve((size_t)NROWS * DINNER * 2);        // 33.6 MB
    u16*   ub      = (u16*)carve((size_t)NROWS * DINNER * 2);        // 33.6 MB
    u16*   delta   = (u16*)carve((size_t)NROWS * DINNER * 2);        // 33.6 MB
    float* xdbl    = (float*)carve((size_t)NROWS * 96 * 4);          //  3.1 MB
    u16*   dtb     = (u16*)carve((size_t)NROWS * DTR * 2);           //  1.0 MB
    float* Sb      = (float*)carve((size_t)NCHUNK * 4 * DINNER * 4); //  2.0 MB
    u16* QH = xn_b;     // 16.8 MB alias; Qb then H0 in place
    u16* gb = xi_b;     // 33.6 MB alias; p3 -> out_proj

    if (ws_size < off) return;  // scratch too small: fail numerics gracefully

    prep_k<<<NROWS / 4 + 6464, 256, 0, stream>>>(
        x, norm_w, norm_b, xn_b,
        in_w, w_in_b, 2 * DINNER * DMODEL,
        out_w, wout_b, DMODEL * DINNER,
        xproj_w, xproj_b, 96 * DINNER,
        dt_w, dtw_b, DINNER * DTR);
    gemm256_in<<<dim3(16, 32), 1024, 0, stream>>>(xn_b, w_in_b, xi_b, z_b, DMODEL);
    conv_silu<<<NROWS / CROWS, 256, 0, stream>>>(xi_b, conv_w, conv_b, ub);
    gemm_xdbl<<<NROWS / 16, 256, 0, stream>>>(ub, xproj_b, xdbl, dtb);
    gemm_nt<2><<<dim3(DINNER / BN, NROWS / BM), 256, 0, stream>>>(
        dtb, dtw_b, nullptr, dt_b, delta, nullptr, NROWS, DINNER, DTR);
    scan_p1<<<BATCH * NCHUNK * (DINNER / 256), 256, 0, stream>>>(
        delta, ub, xdbl, A_log, QH, Sb);
    scan_p2<<<(BATCH * DST * DINNER) / 256, 256, 0, stream>>>(QH, Sb, A_log);
    scan_p3<<<BATCH * NCHUNK * (DINNER / 256), 256, 0, stream>>>(
        delta, ub, xdbl, z_b, A_log, Dp, QH, gb);
    gemm_nt<1><<<dim3(DMODEL / BN, NROWS / BM), 256, 0, stream>>>(
        gb, wout_b, out, x, nullptr, nullptr, NROWS, DMODEL, DINNER);
}